// Round 5
// baseline (339.594 us; speedup 1.0000x reference)
//
#include <hip/hip_runtime.h>

using bf16x8 = __attribute__((ext_vector_type(8))) short;
using f32x4  = __attribute__((ext_vector_type(4))) float;
using f32x16 = __attribute__((ext_vector_type(16))) float;
using u32x4  = __attribute__((ext_vector_type(4))) unsigned int;

#define NPIX 4096
#define CCH  256

__device__ __forceinline__ unsigned short f2bf(float f) {
  unsigned int u = __builtin_bit_cast(unsigned int, f);
  u += 0x7FFFu + ((u >> 16) & 1u);
  return (unsigned short)(u >> 16);
}

__device__ __forceinline__ float bfu(unsigned short h) {
  unsigned int u = ((unsigned int)h) << 16;
  return __builtin_bit_cast(float, u);
}

__device__ __forceinline__ unsigned int pack2(float a, float b) {
  return (unsigned int)f2bf(a) | ((unsigned int)f2bf(b) << 16);
}

// ---------------- W conversion fp32 -> bf16, [3][256][256] ----------------
__global__ __launch_bounds__(256) void convert_w_kernel(
    const float* __restrict__ Wb, const float* __restrict__ Wc,
    const float* __restrict__ Wd, unsigned short* __restrict__ Wbf) {
  const int mat = blockIdx.y;
  const float* src = (mat == 0) ? Wb : (mat == 1) ? Wc : Wd;
  int i = (blockIdx.x * 256 + threadIdx.x) * 4;
  float4 v = *reinterpret_cast<const float4*>(src + i);
  uint2 o;
  o.x = pack2(v.x, v.y);
  o.y = pack2(v.z, v.w);
  *reinterpret_cast<uint2*>(Wbf + mat * 65536 + i) = o;
}

// ---------------- fused transpose + 3 projections ----------------
// K and V are written in PACKED MFMA-TILE ORDER so the attention kernel can
// read fragments directly from global memory with fully-coalesced 1KB wave
// loads (no LDS staging in attn at all):
//   K_packed[n][half][t][s 0..15][hi][l31][16B]   (t = kv-tile of 32 rows)
//     element: kv pix = half*2048 + t*32 + l31, ch = s*16 + hi*8 + b/2
//   V_packed[n][half][t][cb 0..7][kk][hi][l31][16B]
//     element: ch = cb*32 + l31, pix = half*2048 + t*32 + kk*16 + hi*8 + b/2
// Q keeps the [pix][ch] layout (read once per wave into registers).
__global__ __launch_bounds__(256, 2) void fused_proj_kernel(
    const float* __restrict__ x, const unsigned short* __restrict__ Wbf,
    const float* __restrict__ bb, const float* __restrict__ bc,
    const float* __restrict__ bd, unsigned short* __restrict__ Q,
    unsigned short* __restrict__ K, unsigned short* __restrict__ Vt) {
  __shared__ __align__(16) float tile[64][65];   // phase-1 scratch + bounce
  __shared__ __align__(16) char xsub[32768];
  char* bounce = (char*)tile;

  const int tid = threadIdx.x;
  const int wid = tid >> 6, lane = tid & 63;
  const int l31 = lane & 31, hi = lane >> 5;
  const int lt = blockIdx.x, n = blockIdx.y;

  // ---- phase 1: x[n][c][lt*64..] -> bf16 subtiles ----
  #pragma unroll 1
  for (int ct = 0; ct < 4; ++ct) {
    const float* xg = x + ((size_t)(n * CCH + ct * 64)) * NPIX + lt * 64;
    #pragma unroll
    for (int it = 0; it < 4; ++it) {
      int row = (tid >> 4) + it * 16;
      int col = (tid & 15) * 4;
      float4 v = *reinterpret_cast<const float4*>(xg + (size_t)row * NPIX + col);
      tile[row][col] = v.x; tile[row][col + 1] = v.y;
      tile[row][col + 2] = v.z; tile[row][col + 3] = v.w;
    }
    __syncthreads();
    #pragma unroll
    for (int it = 0; it < 2; ++it) {
      int idx = tid + it * 256;
      int l = idx >> 3;
      int ch = (idx & 7) * 8;
      int c = ct * 64 + ch;
      uint4 o;
      o.x = pack2(tile[ch + 0][l], tile[ch + 1][l]);
      o.y = pack2(tile[ch + 2][l], tile[ch + 3][l]);
      o.z = pack2(tile[ch + 4][l], tile[ch + 5][l]);
      o.w = pack2(tile[ch + 6][l], tile[ch + 7][l]);
      int addr = (l >> 5) * 16384 + (c >> 4) * 1024 + ((c >> 3) & 1) * 512 + (l & 31) * 16;
      *reinterpret_cast<uint4*>(xsub + addr) = o;
    }
    __syncthreads();
  }

  // ---- phase 2: wave = o-quarter [wid*64, wid*64+64) ----
  const int o0a = wid * 64, o0b = wid * 64 + 32;
  const size_t pixrow = (size_t)n * NPIX + lt * 64;

  #pragma unroll 1
  for (int mat = 0; mat < 3; ++mat) {
    const unsigned short* W = Wbf + mat * 65536;
    const float* bias = (mat == 0) ? bb : (mat == 1) ? bc : bd;
    f32x16 a00, a01, a10, a11;  // [oi][pix-half]
    #pragma unroll
    for (int e = 0; e < 16; ++e) { a00[e] = 0.f; a01[e] = 0.f; a10[e] = 0.f; a11[e] = 0.f; }
    #pragma unroll
    for (int c0 = 0; c0 < 16; ++c0) {
      bf16x8 x0 = *reinterpret_cast<const bf16x8*>(xsub + c0 * 1024 + lane * 16);
      bf16x8 x1 = *reinterpret_cast<const bf16x8*>(xsub + 16384 + c0 * 1024 + lane * 16);
      bf16x8 w0 = *reinterpret_cast<const bf16x8*>(W + (o0a + l31) * CCH + c0 * 16 + hi * 8);
      bf16x8 w1 = *reinterpret_cast<const bf16x8*>(W + (o0b + l31) * CCH + c0 * 16 + hi * 8);
      if (mat < 2) {
        a00 = __builtin_amdgcn_mfma_f32_32x32x16_bf16(w0, x0, a00, 0, 0, 0);
        a01 = __builtin_amdgcn_mfma_f32_32x32x16_bf16(w0, x1, a01, 0, 0, 0);
        a10 = __builtin_amdgcn_mfma_f32_32x32x16_bf16(w1, x0, a10, 0, 0, 0);
        a11 = __builtin_amdgcn_mfma_f32_32x32x16_bf16(w1, x1, a11, 0, 0, 0);
      } else {
        a00 = __builtin_amdgcn_mfma_f32_32x32x16_bf16(x0, w0, a00, 0, 0, 0);
        a01 = __builtin_amdgcn_mfma_f32_32x32x16_bf16(x1, w0, a01, 0, 0, 0);
        a10 = __builtin_amdgcn_mfma_f32_32x32x16_bf16(x0, w1, a10, 0, 0, 0);
        a11 = __builtin_amdgcn_mfma_f32_32x32x16_bf16(x1, w1, a11, 0, 0, 0);
      }
    }
    if (mat < 2) {
      #pragma unroll 1
      for (int ph = 0; ph < 2; ++ph) {
        __syncthreads();
        const f32x16& A0 = ph ? a01 : a00;
        const f32x16& A1 = ph ? a11 : a10;
        const int swz = (l31 & 15) << 4;
        #pragma unroll
        for (int r2 = 0; r2 < 8; ++r2) {
          const int r = r2 * 2;
          const int od = (r & 3) + 8 * (r >> 2) + 4 * hi;
          const int oa = o0a + od, ob = o0b + od;
          *reinterpret_cast<unsigned int*>(bounce + ((l31 * 512 + oa * 2) ^ swz)) =
              pack2(A0[r] + bias[oa], A0[r + 1] + bias[oa + 1]);
          *reinterpret_cast<unsigned int*>(bounce + ((l31 * 512 + ob * 2) ^ swz)) =
              pack2(A1[r] + bias[ob], A1[r + 1] + bias[ob + 1]);
        }
        __syncthreads();
        const int dp = tid >> 3, obase = (tid & 7) * 32;
        const int dswz = (dp & 15) << 4;
        if (mat == 0) {
          // Q: [pix][ch] layout
          char* gout = (char*)(Q + (pixrow + ph * 32 + dp) * CCH + obase);
          #pragma unroll
          for (int k = 0; k < 4; ++k) {
            u32x4 v = *reinterpret_cast<const u32x4*>(
                bounce + ((dp * 512 + obase * 2 + k * 16) ^ dswz));
            *reinterpret_cast<u32x4*>(gout + k * 16) = v;
          }
        } else {
          // K: packed tile order. 16B (ch obase+k*8, pix-row dp of tile t_k)
          //   -> t_k*16384 + s*1024 + hi*512 + dp*16, s=(tid&7)*2+(k>>1), hi=k&1
          const int t_k = (lt * 2 + ph) & 63;
          const int halfk = lt >> 5;
          char* kout = (char*)K + (size_t)n * 2097152 + (size_t)halfk * 1048576 +
                       t_k * 16384 + dp * 16;
          #pragma unroll
          for (int k = 0; k < 4; ++k) {
            u32x4 v = *reinterpret_cast<const u32x4*>(
                bounce + ((dp * 512 + obase * 2 + k * 16) ^ dswz));
            *reinterpret_cast<u32x4*>(
                kout + ((tid & 7) * 2 + (k >> 1)) * 1024 + (k & 1) * 512) = v;
          }
        }
      }
    } else {
      // ---- V epilogue: single round, both o-halves, packed store ----
      __syncthreads();   // all waves finished xsub MFMA reads; xsub reusable
      {
        char* dstb = (wid >> 1) ? xsub : bounce;
        const int ola = (wid & 1) * 64 + l31;
        const int olb = ola + 32;
        const float bva = bias[o0a + l31], bvb = bias[o0b + l31];
        const int sza = (ola & 7) << 4, szb = (olb & 7) << 4;
        #pragma unroll
        for (int r2 = 0; r2 < 8; ++r2) {
          const int r = r2 * 2;
          const int pd = (r & 3) + 8 * (r >> 2) + 4 * hi;
          *reinterpret_cast<unsigned int*>(dstb + ((ola * 128 + pd * 2) ^ sza)) =
              pack2(a00[r] + bva, a00[r + 1] + bva);
          *reinterpret_cast<unsigned int*>(dstb + ((ola * 128 + (pd + 32) * 2) ^ sza)) =
              pack2(a01[r] + bva, a01[r + 1] + bva);
          *reinterpret_cast<unsigned int*>(dstb + ((olb * 128 + pd * 2) ^ szb)) =
              pack2(a10[r] + bvb, a10[r + 1] + bvb);
          *reinterpret_cast<unsigned int*>(dstb + ((olb * 128 + (pd + 32) * 2) ^ szb)) =
              pack2(a11[r] + bvb, a11[r + 1] + bvb);
        }
      }
      __syncthreads();
      const int ol = tid >> 1, pb0 = (tid & 1) * 32;
      const int vswz = (ol & 7) << 4;
      // packed addr: 16B (ch os*128+ol, pix lt*64+pb0+k*8)
      //   -> tv*16384 + (os*4 + ol>>5)*2048 + (k>>1)*1024 + (k&1)*512 + (ol&31)*16
      const int tv = (lt * 2 + (tid & 1)) & 63;
      const int halfv = lt >> 5;
      char* vout = (char*)Vt + (size_t)n * 2097152 + (size_t)halfv * 1048576 +
                   tv * 16384 + (ol & 31) * 16;
      #pragma unroll
      for (int os = 0; os < 2; ++os) {
        const char* srcb = os ? xsub : bounce;
        char* vo = vout + (os * 4 + (ol >> 5)) * 2048;
        #pragma unroll
        for (int k = 0; k < 4; ++k) {
          u32x4 v = *reinterpret_cast<const u32x4*>(
              srcb + ((ol * 128 + pb0 * 2 + k * 16) ^ vswz));
          *reinterpret_cast<u32x4*>(vo + (k >> 1) * 1024 + (k & 1) * 512) = v;
        }
      }
    }
  }
}

// ---------------- attention partial: LDS-free, packed K/V direct reads ----
// 4 waves x 32 q; KVBLK=32, 64 iters. K/V fragments read straight from
// L1/L2-resident packed tiles with coalesced 1KB wave loads — address math
// identical to the old ds_read (base + slot*1024 + lane*16). No LDS, no DMA,
// no __syncthreads (waves fully independent); one raw s_barrier per iter
// keeps the 4 waves in lockstep so the 16KB tiles stay L1-hot.
__global__ __launch_bounds__(256, 2) void attn_part_kernel(
    const unsigned short* __restrict__ Q, const unsigned short* __restrict__ Kp,
    const unsigned short* __restrict__ Vp, unsigned short* __restrict__ Opart,
    float* __restrict__ lsumbuf) {
  const int tid = threadIdx.x;
  const int wid = tid >> 6;
  const int lane = tid & 63;
  const int l31 = lane & 31;
  const int hi = lane >> 5;
  const int lofs = lane << 4;
  const int blk = blockIdx.x;
  const int n = blk & 7;
  const int t2 = blk >> 3;
  const int half = t2 & 1;
  const int qb = t2 >> 1;
  const int q0 = qb * 128 + wid * 32;

  const unsigned short* Qg = Q + (size_t)n * NPIX * CCH;
  const char* Kb = (const char*)Kp + (size_t)n * 2097152 + (size_t)half * 1048576;
  const char* Vb = (const char*)Vp + (size_t)n * 2097152 + (size_t)half * 1048576;

  bf16x8 qf[16];
  #pragma unroll
  for (int c0 = 0; c0 < 16; ++c0)
    qf[c0] = *reinterpret_cast<const bf16x8*>(
        Qg + (size_t)(q0 + l31) * CCH + c0 * 16 + hi * 8);

  f32x16 oacc[8];
  #pragma unroll
  for (int i = 0; i < 8; ++i)
    #pragma unroll
    for (int e = 0; e < 16; ++e) oacc[i][e] = 0.f;
  float lsum = 0.f;

  #pragma unroll 1
  for (int t = 0; t < 64; ++t) {
    const char* kt = Kb + t * 16384;
    const char* vt = Vb + t * 16384;

    f32x16 S;
    #pragma unroll
    for (int e = 0; e < 16; ++e) S[e] = 0.f;
    __builtin_amdgcn_s_setprio(1);
    #pragma unroll
    for (int c0 = 0; c0 < 16; ++c0) {
      bf16x8 kf = *reinterpret_cast<const bf16x8*>(kt + c0 * 1024 + lofs);
      S = __builtin_amdgcn_mfma_f32_32x32x16_bf16(kf, qf[c0], S, 0, 0, 0);
    }
    __builtin_amdgcn_s_setprio(0);

    // ---- fixed-offset softmax: P = exp2(S*log2e - 101), pack via cvt_pk ----
    float rsum = 0.f;
    unsigned int pw[8];
    #pragma unroll
    for (int i = 0; i < 8; ++i) {
      float p0 = exp2f(fmaf(S[2 * i],     1.44269504f, -101.0f));
      float p1 = exp2f(fmaf(S[2 * i + 1], 1.44269504f, -101.0f));
      rsum += p0 + p1;
      unsigned int r;
      asm("v_cvt_pk_bf16_f32 %0, %1, %2" : "=v"(r) : "v"(p0), "v"(p1));
      pw[i] = r;
    }
    lsum += rsum;

    // ---- P re-layout via permlane32_swap ----
    unsigned int s0a = pw[0], s0b = pw[2];
    unsigned int s1a = pw[1], s1b = pw[3];
    unsigned int s2a = pw[4], s2b = pw[6];
    unsigned int s3a = pw[5], s3b = pw[7];
    asm volatile("v_permlane32_swap_b32 %0, %1" : "+v"(s0a), "+v"(s0b));
    asm volatile("v_permlane32_swap_b32 %0, %1" : "+v"(s1a), "+v"(s1b));
    asm volatile("v_permlane32_swap_b32 %0, %1" : "+v"(s2a), "+v"(s2b));
    asm volatile("v_permlane32_swap_b32 %0, %1" : "+v"(s3a), "+v"(s3b));
    u32x4 f0, f1;
    f0[0] = s0a; f0[1] = s1a; f0[2] = s0b; f0[3] = s1b;
    f1[0] = s2a; f1[1] = s3a; f1[2] = s2b; f1[3] = s3b;
    bf16x8 pa0 = __builtin_bit_cast(bf16x8, f0);
    bf16x8 pa1 = __builtin_bit_cast(bf16x8, f1);

    __builtin_amdgcn_s_setprio(1);
    #pragma unroll
    for (int cb = 0; cb < 8; ++cb) {
      bf16x8 v0 = *reinterpret_cast<const bf16x8*>(vt + (cb * 2 + 0) * 1024 + lofs);
      oacc[cb] = __builtin_amdgcn_mfma_f32_32x32x16_bf16(pa0, v0, oacc[cb], 0, 0, 0);
    }
    #pragma unroll
    for (int cb = 0; cb < 8; ++cb) {
      bf16x8 v1 = *reinterpret_cast<const bf16x8*>(vt + (cb * 2 + 1) * 1024 + lofs);
      oacc[cb] = __builtin_amdgcn_mfma_f32_32x32x16_bf16(pa1, v1, oacc[cb], 0, 0, 0);
    }
    __builtin_amdgcn_s_setprio(0);

    __builtin_amdgcn_s_barrier();   // L1-locality lockstep (no data hazard)
  }

  lsum += __shfl_xor(lsum, 32);
  char* slab = (char*)Opart + (size_t)blk * 65536;
  #pragma unroll
  for (int cb = 0; cb < 8; ++cb) {
    u32x4 u0, u1;
    u0[0] = pack2(oacc[cb][0],  oacc[cb][1]);
    u0[1] = pack2(oacc[cb][2],  oacc[cb][3]);
    u0[2] = pack2(oacc[cb][4],  oacc[cb][5]);
    u0[3] = pack2(oacc[cb][6],  oacc[cb][7]);
    u1[0] = pack2(oacc[cb][8],  oacc[cb][9]);
    u1[1] = pack2(oacc[cb][10], oacc[cb][11]);
    u1[2] = pack2(oacc[cb][12], oacc[cb][13]);
    u1[3] = pack2(oacc[cb][14], oacc[cb][15]);
    *reinterpret_cast<u32x4*>(slab + (cb * 2 + 0) * 4096 + tid * 16) = u0;
    *reinterpret_cast<u32x4*>(slab + (cb * 2 + 1) * 4096 + tid * 16) = u1;
  }
  if (hi == 0) lsumbuf[blk * 128 + wid * 32 + l31] = lsum;
}

// ---------------- merge halves + normalize + residual + transpose ----------------
__global__ __launch_bounds__(512) void merge_kernel(
    const unsigned short* __restrict__ Opart, const float* __restrict__ lsumbuf,
    const float* __restrict__ x, const float* __restrict__ alpha_p,
    float* __restrict__ out) {
  __shared__ float T[32768];   // [c 0..255][q' 0..127], elem = c*128 + (q'^(c&28))
  __shared__ float Lq[128];

  const int tid = threadIdx.x;
  const int pr8 = tid >> 6;
  const int lane = tid & 63;
  const int l31 = lane & 31;
  const int hi = lane >> 5;
  const int qsub = pr8 & 3;
  const int cbh = pr8 >> 2;
  const int atid = qsub * 64 + lane;    // matching attn-slab thread index
  const int m = blockIdx.x;
  const int n = m & 7;
  const int qb = m >> 3;
  const int blkA = n + 8 * (0 + 2 * qb);
  const int blkB = n + 8 * (1 + 2 * qb);

  if (tid < 128)
    Lq[tid] = alpha_p[0] / (lsumbuf[blkA * 128 + tid] + lsumbuf[blkB * 128 + tid]);
  __syncthreads();

  const char* sa = (const char*)Opart + (size_t)blkA * 65536;
  const char* sb = (const char*)Opart + (size_t)blkB * 65536;

  #pragma unroll
  for (int cbi = 0; cbi < 4; ++cbi) {
    const int cb = cbh * 4 + cbi;
    const int c = cb * 32 + l31;
    const int swz = c & 28;
    #pragma unroll
    for (int h = 0; h < 2; ++h) {
      u32x4 a = *reinterpret_cast<const u32x4*>(sa + (cb * 2 + h) * 4096 + atid * 16);
      u32x4 b = *reinterpret_cast<const u32x4*>(sb + (cb * 2 + h) * 4096 + atid * 16);
      #pragma unroll
      for (int w = 0; w < 4; ++w) {
        const int r = h * 8 + w * 2;
        float v0 = bfu((unsigned short)(a[w] & 0xFFFF)) + bfu((unsigned short)(b[w] & 0xFFFF));
        float v1 = bfu((unsigned short)(a[w] >> 16)) + bfu((unsigned short)(b[w] >> 16));
        const int q0l = qsub * 32 + ((r) & 3) + 8 * ((r) >> 2) + 4 * hi;
        const int q1l = q0l + 1;
        T[c * 128 + (q0l ^ swz)] = v0 * Lq[q0l];
        T[c * 128 + (q1l ^ swz)] = v1 * Lq[q1l];
      }
    }
  }
  __syncthreads();

  // write out: 16 sweeps, 16 c-rows per sweep, float4 per thread
  const int l0 = (tid & 31) * 4;
  #pragma unroll 4
  for (int sw = 0; sw < 16; ++sw) {
    const int c = (tid >> 5) + sw * 16;
    const float* src = &T[c * 128 + (l0 ^ (c & 28))];
    float4 v = *reinterpret_cast<const float4*>(src);
    const size_t g = ((size_t)n * CCH + c) * NPIX + qb * 128 + l0;
    float4 xi = *reinterpret_cast<const float4*>(x + g);
    float4 o;
    o.x = v.x + xi.x; o.y = v.y + xi.y; o.z = v.z + xi.z; o.w = v.w + xi.w;
    *reinterpret_cast<float4*>(out + g) = o;
  }
}

extern "C" void kernel_launch(void* const* d_in, const int* in_sizes, int n_in,
                              void* d_out, int out_size, void* d_ws, size_t ws_size,
                              hipStream_t stream) {
  const float* x  = (const float*)d_in[0];
  const float* Wb = (const float*)d_in[1];
  const float* bb = (const float*)d_in[2];
  const float* Wc = (const float*)d_in[3];
  const float* bc = (const float*)d_in[4];
  const float* Wd = (const float*)d_in[5];
  const float* bd = (const float*)d_in[6];
  const float* alpha = (const float*)d_in[7];
  float* out = (float*)d_out;
  char* ws = (char*)d_ws;

  unsigned short* Wbf   = (unsigned short*)(ws);                //    393,216 B
  unsigned short* Q     = (unsigned short*)(ws + 393216);       // 16,777,216 B
  unsigned short* K     = (unsigned short*)(ws + 17170432);     // 16,777,216 B (packed)
  unsigned short* Vt    = (unsigned short*)(ws + 33947648);     // 16,777,216 B (packed)
  unsigned short* Opart = (unsigned short*)(ws + 50724864);     // 33,554,432 B
  float*          lsumb = (float*)(ws + 84279296);              //    262,144 B

  convert_w_kernel<<<dim3(64, 3), 256, 0, stream>>>(Wb, Wc, Wd, Wbf);
  fused_proj_kernel<<<dim3(64, 8), 256, 0, stream>>>(x, Wbf, bb, bc, bd, Q, K, Vt);
  attn_part_kernel<<<dim3(512), 256, 0, stream>>>(Q, K, Vt, Opart, lsumb);
  merge_kernel<<<dim3(256), 512, 0, stream>>>(Opart, lsumb, x, alpha, out);
}

// Round 6
// 215.606 us; speedup vs baseline: 1.5751x; 1.5751x over previous
//
#include <hip/hip_runtime.h>

using bf16x8 = __attribute__((ext_vector_type(8))) short;
using f32x4  = __attribute__((ext_vector_type(4))) float;
using f32x16 = __attribute__((ext_vector_type(16))) float;
using u32x4  = __attribute__((ext_vector_type(4))) unsigned int;

#define NPIX 4096
#define CCH  256

__device__ __forceinline__ unsigned short f2bf(float f) {
  unsigned int u = __builtin_bit_cast(unsigned int, f);
  u += 0x7FFFu + ((u >> 16) & 1u);
  return (unsigned short)(u >> 16);
}

__device__ __forceinline__ float bfu(unsigned short h) {
  unsigned int u = ((unsigned int)h) << 16;
  return __builtin_bit_cast(float, u);
}

__device__ __forceinline__ unsigned int pack2(float a, float b) {
  return (unsigned int)f2bf(a) | ((unsigned int)f2bf(b) << 16);
}

__device__ __forceinline__ void gld_lds16(const void* g, void* l) {
  __builtin_amdgcn_global_load_lds(
      (const __attribute__((address_space(1))) unsigned int*)g,
      (__attribute__((address_space(3))) unsigned int*)l, 16, 0, 0);
}

// ---------------- W conversion fp32 -> bf16, [3][256][256] ----------------
__global__ __launch_bounds__(256) void convert_w_kernel(
    const float* __restrict__ Wb, const float* __restrict__ Wc,
    const float* __restrict__ Wd, unsigned short* __restrict__ Wbf) {
  const int mat = blockIdx.y;
  const float* src = (mat == 0) ? Wb : (mat == 1) ? Wc : Wd;
  int i = (blockIdx.x * 256 + threadIdx.x) * 4;
  float4 v = *reinterpret_cast<const float4*>(src + i);
  uint2 o;
  o.x = pack2(v.x, v.y);
  o.y = pack2(v.z, v.w);
  *reinterpret_cast<uint2*>(Wbf + mat * 65536 + i) = o;
}

// ---------------- fused transpose + 3 projections (coalesced stores) ----------
// tile stride 65 floats: phase-1 col reads step 8 rows -> banks spread 2-way
// (free). 16B-aligned strides (64+4k) would make the 8-row step single-bank.
// V epilogue: single round -- waves write their o-quarter into {bounce, xsub}
// (xsub is dead after mat 2's MFMA reads), then one sweep stores both halves.
__global__ __launch_bounds__(256, 2) void fused_proj_kernel(
    const float* __restrict__ x, const unsigned short* __restrict__ Wbf,
    const float* __restrict__ bb, const float* __restrict__ bc,
    const float* __restrict__ bd, unsigned short* __restrict__ Q,
    unsigned short* __restrict__ K, unsigned short* __restrict__ Vt) {
  __shared__ __align__(16) float tile[64][65];   // phase-1 scratch + bounce
  __shared__ __align__(16) char xsub[32768];
  char* bounce = (char*)tile;

  const int tid = threadIdx.x;
  const int wid = tid >> 6, lane = tid & 63;
  const int l31 = lane & 31, hi = lane >> 5;
  const int lt = blockIdx.x, n = blockIdx.y;

  // ---- phase 1: x[n][c][lt*64..] -> bf16 subtiles ----
  #pragma unroll 1
  for (int ct = 0; ct < 4; ++ct) {
    const float* xg = x + ((size_t)(n * CCH + ct * 64)) * NPIX + lt * 64;
    #pragma unroll
    for (int it = 0; it < 4; ++it) {
      int row = (tid >> 4) + it * 16;
      int col = (tid & 15) * 4;
      float4 v = *reinterpret_cast<const float4*>(xg + (size_t)row * NPIX + col);
      tile[row][col] = v.x; tile[row][col + 1] = v.y;
      tile[row][col + 2] = v.z; tile[row][col + 3] = v.w;
    }
    __syncthreads();
    #pragma unroll
    for (int it = 0; it < 2; ++it) {
      int idx = tid + it * 256;
      int l = idx >> 3;
      int ch = (idx & 7) * 8;
      int c = ct * 64 + ch;
      uint4 o;
      o.x = pack2(tile[ch + 0][l], tile[ch + 1][l]);
      o.y = pack2(tile[ch + 2][l], tile[ch + 3][l]);
      o.z = pack2(tile[ch + 4][l], tile[ch + 5][l]);
      o.w = pack2(tile[ch + 6][l], tile[ch + 7][l]);
      int addr = (l >> 5) * 16384 + (c >> 4) * 1024 + ((c >> 3) & 1) * 512 + (l & 31) * 16;
      *reinterpret_cast<uint4*>(xsub + addr) = o;
    }
    __syncthreads();
  }

  // ---- phase 2: wave = o-quarter [wid*64, wid*64+64) ----
  const int o0a = wid * 64, o0b = wid * 64 + 32;
  const size_t pixrow = (size_t)n * NPIX + lt * 64;

  #pragma unroll 1
  for (int mat = 0; mat < 3; ++mat) {
    const unsigned short* W = Wbf + mat * 65536;
    const float* bias = (mat == 0) ? bb : (mat == 1) ? bc : bd;
    f32x16 a00, a01, a10, a11;  // [oi][pix-half]
    #pragma unroll
    for (int e = 0; e < 16; ++e) { a00[e] = 0.f; a01[e] = 0.f; a10[e] = 0.f; a11[e] = 0.f; }
    #pragma unroll
    for (int c0 = 0; c0 < 16; ++c0) {
      bf16x8 x0 = *reinterpret_cast<const bf16x8*>(xsub + c0 * 1024 + lane * 16);
      bf16x8 x1 = *reinterpret_cast<const bf16x8*>(xsub + 16384 + c0 * 1024 + lane * 16);
      bf16x8 w0 = *reinterpret_cast<const bf16x8*>(W + (o0a + l31) * CCH + c0 * 16 + hi * 8);
      bf16x8 w1 = *reinterpret_cast<const bf16x8*>(W + (o0b + l31) * CCH + c0 * 16 + hi * 8);
      if (mat < 2) {
        a00 = __builtin_amdgcn_mfma_f32_32x32x16_bf16(w0, x0, a00, 0, 0, 0);
        a01 = __builtin_amdgcn_mfma_f32_32x32x16_bf16(w0, x1, a01, 0, 0, 0);
        a10 = __builtin_amdgcn_mfma_f32_32x32x16_bf16(w1, x0, a10, 0, 0, 0);
        a11 = __builtin_amdgcn_mfma_f32_32x32x16_bf16(w1, x1, a11, 0, 0, 0);
      } else {
        a00 = __builtin_amdgcn_mfma_f32_32x32x16_bf16(x0, w0, a00, 0, 0, 0);
        a01 = __builtin_amdgcn_mfma_f32_32x32x16_bf16(x1, w0, a01, 0, 0, 0);
        a10 = __builtin_amdgcn_mfma_f32_32x32x16_bf16(x0, w1, a10, 0, 0, 0);
        a11 = __builtin_amdgcn_mfma_f32_32x32x16_bf16(x1, w1, a11, 0, 0, 0);
      }
    }
    if (mat < 2) {
      unsigned short* dst = (mat == 0) ? Q : K;
      #pragma unroll 1
      for (int ph = 0; ph < 2; ++ph) {
        __syncthreads();
        const f32x16& A0 = ph ? a01 : a00;
        const f32x16& A1 = ph ? a11 : a10;
        const int swz = (l31 & 15) << 4;
        #pragma unroll
        for (int r2 = 0; r2 < 8; ++r2) {
          const int r = r2 * 2;
          const int od = (r & 3) + 8 * (r >> 2) + 4 * hi;
          const int oa = o0a + od, ob = o0b + od;
          *reinterpret_cast<unsigned int*>(bounce + ((l31 * 512 + oa * 2) ^ swz)) =
              pack2(A0[r] + bias[oa], A0[r + 1] + bias[oa + 1]);
          *reinterpret_cast<unsigned int*>(bounce + ((l31 * 512 + ob * 2) ^ swz)) =
              pack2(A1[r] + bias[ob], A1[r + 1] + bias[ob + 1]);
        }
        __syncthreads();
        const int dp = tid >> 3, obase = (tid & 7) * 32;
        const int dswz = (dp & 15) << 4;
        char* gout = (char*)(dst + (pixrow + ph * 32 + dp) * CCH + obase);
        #pragma unroll
        for (int k = 0; k < 4; ++k) {
          u32x4 v = *reinterpret_cast<const u32x4*>(
              bounce + ((dp * 512 + obase * 2 + k * 16) ^ dswz));
          *reinterpret_cast<u32x4*>(gout + k * 16) = v;
        }
      }
    } else {
      // ---- V epilogue: single round, both o-halves concurrently ----
      __syncthreads();   // all waves finished xsub MFMA reads; xsub reusable
      {
        char* dstb = (wid >> 1) ? xsub : bounce;
        const int ola = (wid & 1) * 64 + l31;   // o0a + l31 - (wid>>1)*128
        const int olb = ola + 32;
        const float bva = bias[o0a + l31], bvb = bias[o0b + l31];
        const int sza = (ola & 7) << 4, szb = (olb & 7) << 4;
        #pragma unroll
        for (int r2 = 0; r2 < 8; ++r2) {
          const int r = r2 * 2;
          const int pd = (r & 3) + 8 * (r >> 2) + 4 * hi;
          *reinterpret_cast<unsigned int*>(dstb + ((ola * 128 + pd * 2) ^ sza)) =
              pack2(a00[r] + bva, a00[r + 1] + bva);
          *reinterpret_cast<unsigned int*>(dstb + ((ola * 128 + (pd + 32) * 2) ^ sza)) =
              pack2(a01[r] + bva, a01[r + 1] + bva);
          *reinterpret_cast<unsigned int*>(dstb + ((olb * 128 + pd * 2) ^ szb)) =
              pack2(a10[r] + bvb, a10[r + 1] + bvb);
          *reinterpret_cast<unsigned int*>(dstb + ((olb * 128 + (pd + 32) * 2) ^ szb)) =
              pack2(a11[r] + bvb, a11[r + 1] + bvb);
        }
      }
      __syncthreads();
      const int ol = tid >> 1, pb0 = (tid & 1) * 32;
      const int vswz = (ol & 7) << 4;
      #pragma unroll
      for (int os = 0; os < 2; ++os) {
        const char* srcb = os ? xsub : bounce;
        char* gout = (char*)(Vt + ((size_t)(n * CCH + os * 128 + ol)) * NPIX + lt * 64 + pb0);
        #pragma unroll
        for (int k = 0; k < 4; ++k) {
          u32x4 v = *reinterpret_cast<const u32x4*>(
              srcb + ((ol * 128 + pb0 * 2 + k * 16) ^ vswz));
          *reinterpret_cast<u32x4*>(gout + k * 16) = v;
        }
      }
    }
  }
}

// ---------------- attention partial: one j-half per block ----------------
// 4 waves x 32 q; KVBLK=32, 64 iters, dbuf 2x32KB -> 2 blocks/CU (R4 base,
// best measured). NEW: QK^T accumulates into TWO checkerboard accumulators
// (S0 even c0, S1 odd c0) -> dep-chain depth 8 instead of 16; combined with
// 16 v_add_f32. Pure f32 reassociation (numerics unchanged at bf16 level).
__global__ __launch_bounds__(256, 2) void attn_part_kernel(
    const unsigned short* __restrict__ Q, const unsigned short* __restrict__ K,
    const unsigned short* __restrict__ Vt, unsigned short* __restrict__ Opart,
    float* __restrict__ lsumbuf) {
  __shared__ __align__(16) char smem[65536];

  const int tid = threadIdx.x;
  const int wid = tid >> 6;
  const int lane = tid & 63;
  const int l31 = lane & 31;
  const int hi = lane >> 5;
  const int lofs = lane << 4;
  const int blk = blockIdx.x;
  const int n = blk & 7;
  const int t2 = blk >> 3;
  const int half = t2 & 1;
  const int qb = t2 >> 1;
  const int q0 = qb * 128 + wid * 32;

  const unsigned short* Qg = Q + (size_t)n * NPIX * CCH;
  const char* Kg = (const char*)(K + ((size_t)n * NPIX + half * 2048) * CCH);
  const char* Vg = (const char*)(Vt + (size_t)n * CCH * NPIX + half * 2048);

  bf16x8 qf[16];
  #pragma unroll
  for (int c0 = 0; c0 < 16; ++c0)
    qf[c0] = *reinterpret_cast<const bf16x8*>(
        Qg + (size_t)(q0 + l31) * CCH + c0 * 16 + hi * 8);

  f32x16 oacc[8];
  #pragma unroll
  for (int i = 0; i < 8; ++i)
    #pragma unroll
    for (int e = 0; e < 16; ++e) oacc[i][e] = 0.f;
  float lsum = 0.f;

  const bool isK = wid < 2;
  const char* splane = isK ? Kg : Vg;
  const int sinc = isK ? 32 * 512 : 64;
  int soff[8];
  #pragma unroll
  for (int g = 0; g < 8; ++g) {
    int s = ((wid & 1) << 3) + g;
    if (isK) {
      soff[g] = l31 * 512 + s * 32 + hi * 16;
    } else {
      int cb = s >> 1, kk2 = s & 1;
      soff[g] = (cb * 32 + l31) * 8192 + (kk2 * 16 + hi * 8) * 2;
    }
  }

  auto STAGE = [&](int par, int adv) {
    #pragma unroll
    for (int g = 0; g < 8; ++g)
      gld_lds16(splane + (size_t)soff[g] + (size_t)adv,
                smem + par * 32768 + (((wid << 3) + g) << 10));
  };

  STAGE(0, 0);
  __syncthreads();

  #pragma unroll 1
  for (int t = 0; t < 64; ++t) {
    const int par = t & 1;
    const char* kb = smem + par * 32768;
    const char* vb = kb + 16384;

    f32x16 S0, S1;
    #pragma unroll
    for (int e = 0; e < 16; ++e) { S0[e] = 0.f; S1[e] = 0.f; }
    __builtin_amdgcn_s_setprio(1);
    #pragma unroll
    for (int c2 = 0; c2 < 8; ++c2) {
      bf16x8 kf0 = *reinterpret_cast<const bf16x8*>(kb + (c2 * 2 + 0) * 1024 + lofs);
      S0 = __builtin_amdgcn_mfma_f32_32x32x16_bf16(kf0, qf[c2 * 2 + 0], S0, 0, 0, 0);
      bf16x8 kf1 = *reinterpret_cast<const bf16x8*>(kb + (c2 * 2 + 1) * 1024 + lofs);
      S1 = __builtin_amdgcn_mfma_f32_32x32x16_bf16(kf1, qf[c2 * 2 + 1], S1, 0, 0, 0);
    }
    __builtin_amdgcn_s_setprio(0);

    // prefetch of next tile issued while softmax runs
    if (t < 63) STAGE(par ^ 1, (t + 1) * sinc);

    f32x16 S;
    #pragma unroll
    for (int e = 0; e < 16; ++e) S[e] = S0[e] + S1[e];

    // ---- fixed-offset softmax: P = exp2(S*log2e - 101), pack via cvt_pk ----
    float rsum = 0.f;
    unsigned int pw[8];
    #pragma unroll
    for (int i = 0; i < 8; ++i) {
      float p0 = exp2f(fmaf(S[2 * i],     1.44269504f, -101.0f));
      float p1 = exp2f(fmaf(S[2 * i + 1], 1.44269504f, -101.0f));
      rsum += p0 + p1;
      unsigned int r;
      asm("v_cvt_pk_bf16_f32 %0, %1, %2" : "=v"(r) : "v"(p0), "v"(p1));
      pw[i] = r;
    }
    lsum += rsum;

    // ---- P re-layout via permlane32_swap ----
    unsigned int s0a = pw[0], s0b = pw[2];
    unsigned int s1a = pw[1], s1b = pw[3];
    unsigned int s2a = pw[4], s2b = pw[6];
    unsigned int s3a = pw[5], s3b = pw[7];
    asm volatile("v_permlane32_swap_b32 %0, %1" : "+v"(s0a), "+v"(s0b));
    asm volatile("v_permlane32_swap_b32 %0, %1" : "+v"(s1a), "+v"(s1b));
    asm volatile("v_permlane32_swap_b32 %0, %1" : "+v"(s2a), "+v"(s2b));
    asm volatile("v_permlane32_swap_b32 %0, %1" : "+v"(s3a), "+v"(s3b));
    u32x4 f0, f1;
    f0[0] = s0a; f0[1] = s1a; f0[2] = s0b; f0[3] = s1b;
    f1[0] = s2a; f1[1] = s3a; f1[2] = s2b; f1[3] = s3b;
    bf16x8 pa0 = __builtin_bit_cast(bf16x8, f0);
    bf16x8 pa1 = __builtin_bit_cast(bf16x8, f1);

    __builtin_amdgcn_s_setprio(1);
    #pragma unroll
    for (int cb = 0; cb < 8; ++cb) {
      bf16x8 v0 = *reinterpret_cast<const bf16x8*>(vb + (cb * 2 + 0) * 1024 + lofs);
      oacc[cb] = __builtin_amdgcn_mfma_f32_32x32x16_bf16(pa0, v0, oacc[cb], 0, 0, 0);
    }
    #pragma unroll
    for (int cb = 0; cb < 8; ++cb) {
      bf16x8 v1 = *reinterpret_cast<const bf16x8*>(vb + (cb * 2 + 1) * 1024 + lofs);
      oacc[cb] = __builtin_amdgcn_mfma_f32_32x32x16_bf16(pa1, v1, oacc[cb], 0, 0, 0);
    }
    __builtin_amdgcn_s_setprio(0);

    __syncthreads();
  }

  lsum += __shfl_xor(lsum, 32);
  char* slab = (char*)Opart + (size_t)blk * 65536;
  #pragma unroll
  for (int cb = 0; cb < 8; ++cb) {
    u32x4 u0, u1;
    u0[0] = pack2(oacc[cb][0],  oacc[cb][1]);
    u0[1] = pack2(oacc[cb][2],  oacc[cb][3]);
    u0[2] = pack2(oacc[cb][4],  oacc[cb][5]);
    u0[3] = pack2(oacc[cb][6],  oacc[cb][7]);
    u1[0] = pack2(oacc[cb][8],  oacc[cb][9]);
    u1[1] = pack2(oacc[cb][10], oacc[cb][11]);
    u1[2] = pack2(oacc[cb][12], oacc[cb][13]);
    u1[3] = pack2(oacc[cb][14], oacc[cb][15]);
    *reinterpret_cast<u32x4*>(slab + (cb * 2 + 0) * 4096 + tid * 16) = u0;
    *reinterpret_cast<u32x4*>(slab + (cb * 2 + 1) * 4096 + tid * 16) = u1;
  }
  if (hi == 0) lsumbuf[blk * 128 + wid * 32 + l31] = lsum;
}

// ---------------- merge halves + normalize + residual + transpose ----------------
__global__ __launch_bounds__(512) void merge_kernel(
    const unsigned short* __restrict__ Opart, const float* __restrict__ lsumbuf,
    const float* __restrict__ x, const float* __restrict__ alpha_p,
    float* __restrict__ out) {
  __shared__ float T[32768];   // [c 0..255][q' 0..127], elem = c*128 + (q'^(c&28))
  __shared__ float Lq[128];

  const int tid = threadIdx.x;
  const int pr8 = tid >> 6;
  const int lane = tid & 63;
  const int l31 = lane & 31;
  const int hi = lane >> 5;
  const int qsub = pr8 & 3;
  const int cbh = pr8 >> 2;
  const int atid = qsub * 64 + lane;    // matching attn-slab thread index
  const int m = blockIdx.x;
  const int n = m & 7;
  const int qb = m >> 3;
  const int blkA = n + 8 * (0 + 2 * qb);
  const int blkB = n + 8 * (1 + 2 * qb);

  if (tid < 128)
    Lq[tid] = alpha_p[0] / (lsumbuf[blkA * 128 + tid] + lsumbuf[blkB * 128 + tid]);
  __syncthreads();

  const char* sa = (const char*)Opart + (size_t)blkA * 65536;
  const char* sb = (const char*)Opart + (size_t)blkB * 65536;

  #pragma unroll
  for (int cbi = 0; cbi < 4; ++cbi) {
    const int cb = cbh * 4 + cbi;
    const int c = cb * 32 + l31;
    const int swz = c & 28;
    #pragma unroll
    for (int h = 0; h < 2; ++h) {
      u32x4 a = *reinterpret_cast<const u32x4*>(sa + (cb * 2 + h) * 4096 + atid * 16);
      u32x4 b = *reinterpret_cast<const u32x4*>(sb + (cb * 2 + h) * 4096 + atid * 16);
      #pragma unroll
      for (int w = 0; w < 4; ++w) {
        const int r = h * 8 + w * 2;
        float v0 = bfu((unsigned short)(a[w] & 0xFFFF)) + bfu((unsigned short)(b[w] & 0xFFFF));
        float v1 = bfu((unsigned short)(a[w] >> 16)) + bfu((unsigned short)(b[w] >> 16));
        const int q0l = qsub * 32 + ((r) & 3) + 8 * ((r) >> 2) + 4 * hi;
        const int q1l = q0l + 1;
        T[c * 128 + (q0l ^ swz)] = v0 * Lq[q0l];
        T[c * 128 + (q1l ^ swz)] = v1 * Lq[q1l];
      }
    }
  }
  __syncthreads();

  // write out: 16 sweeps, 16 c-rows per sweep, float4 per thread
  const int l0 = (tid & 31) * 4;
  #pragma unroll 4
  for (int sw = 0; sw < 16; ++sw) {
    const int c = (tid >> 5) + sw * 16;
    const float* src = &T[c * 128 + (l0 ^ (c & 28))];
    float4 v = *reinterpret_cast<const float4*>(src);
    const size_t g = ((size_t)n * CCH + c) * NPIX + qb * 128 + l0;
    float4 xi = *reinterpret_cast<const float4*>(x + g);
    float4 o;
    o.x = v.x + xi.x; o.y = v.y + xi.y; o.z = v.z + xi.z; o.w = v.w + xi.w;
    *reinterpret_cast<float4*>(out + g) = o;
  }
}

extern "C" void kernel_launch(void* const* d_in, const int* in_sizes, int n_in,
                              void* d_out, int out_size, void* d_ws, size_t ws_size,
                              hipStream_t stream) {
  const float* x  = (const float*)d_in[0];
  const float* Wb = (const float*)d_in[1];
  const float* bb = (const float*)d_in[2];
  const float* Wc = (const float*)d_in[3];
  const float* bc = (const float*)d_in[4];
  const float* Wd = (const float*)d_in[5];
  const float* bd = (const float*)d_in[6];
  const float* alpha = (const float*)d_in[7];
  float* out = (float*)d_out;
  char* ws = (char*)d_ws;

  unsigned short* Wbf   = (unsigned short*)(ws);                //    393,216 B
  unsigned short* Q     = (unsigned short*)(ws + 393216);       // 16,777,216 B
  unsigned short* K     = (unsigned short*)(ws + 17170432);     // 16,777,216 B
  unsigned short* Vt    = (unsigned short*)(ws + 33947648);     // 16,777,216 B
  unsigned short* Opart = (unsigned short*)(ws + 50724864);     // 33,554,432 B
  float*          lsumb = (float*)(ws + 84279296);              //    262,144 B

  convert_w_kernel<<<dim3(64, 3), 256, 0, stream>>>(Wb, Wc, Wd, Wbf);
  fused_proj_kernel<<<dim3(64, 8), 256, 0, stream>>>(x, Wbf, bb, bc, bd, Q, K, Vt);
  attn_part_kernel<<<dim3(512), 256, 0, stream>>>(Q, K, Vt, Opart, lsumb);
  merge_kernel<<<dim3(256), 512, 0, stream>>>(Opart, lsumb, x, alpha, out);
}

// Round 7
// 214.904 us; speedup vs baseline: 1.5802x; 1.0033x over previous
//
#include <hip/hip_runtime.h>

using bf16x8 = __attribute__((ext_vector_type(8))) short;
using f32x4  = __attribute__((ext_vector_type(4))) float;
using f32x16 = __attribute__((ext_vector_type(16))) float;
using u32x4  = __attribute__((ext_vector_type(4))) unsigned int;

#define NPIX 4096
#define CCH  256

__device__ __forceinline__ unsigned short f2bf(float f) {
  unsigned int u = __builtin_bit_cast(unsigned int, f);
  u += 0x7FFFu + ((u >> 16) & 1u);
  return (unsigned short)(u >> 16);
}

__device__ __forceinline__ float bfu(unsigned short h) {
  unsigned int u = ((unsigned int)h) << 16;
  return __builtin_bit_cast(float, u);
}

__device__ __forceinline__ unsigned int pack2(float a, float b) {
  return (unsigned int)f2bf(a) | ((unsigned int)f2bf(b) << 16);
}

__device__ __forceinline__ void gld_lds16(const void* g, void* l) {
  __builtin_amdgcn_global_load_lds(
      (const __attribute__((address_space(1))) unsigned int*)g,
      (__attribute__((address_space(3))) unsigned int*)l, 16, 0, 0);
}

// ---------------- W conversion fp32 -> bf16, [3][256][256] ----------------
__global__ __launch_bounds__(256) void convert_w_kernel(
    const float* __restrict__ Wb, const float* __restrict__ Wc,
    const float* __restrict__ Wd, unsigned short* __restrict__ Wbf) {
  const int mat = blockIdx.y;
  const float* src = (mat == 0) ? Wb : (mat == 1) ? Wc : Wd;
  int i = (blockIdx.x * 256 + threadIdx.x) * 4;
  float4 v = *reinterpret_cast<const float4*>(src + i);
  uint2 o;
  o.x = pack2(v.x, v.y);
  o.y = pack2(v.z, v.w);
  *reinterpret_cast<uint2*>(Wbf + mat * 65536 + i) = o;
}

// ---------------- fused transpose + 3 projections (coalesced stores) ----------
// tile stride 65 floats: phase-1 col reads step 8 rows -> banks spread 2-way
// (free). 16B-aligned strides (64+4k) would make the 8-row step single-bank
// (8-way conflict) -- do not "fix" the pad for b128 writes (R3 lesson).
// V epilogue: single round -- waves write their o-quarter into {bounce, xsub}
// (xsub is dead after mat 2's MFMA reads), then one sweep stores both halves.
__global__ __launch_bounds__(256, 2) void fused_proj_kernel(
    const float* __restrict__ x, const unsigned short* __restrict__ Wbf,
    const float* __restrict__ bb, const float* __restrict__ bc,
    const float* __restrict__ bd, unsigned short* __restrict__ Q,
    unsigned short* __restrict__ K, unsigned short* __restrict__ Vt) {
  __shared__ __align__(16) float tile[64][65];   // phase-1 scratch + bounce
  __shared__ __align__(16) char xsub[32768];
  char* bounce = (char*)tile;

  const int tid = threadIdx.x;
  const int wid = tid >> 6, lane = tid & 63;
  const int l31 = lane & 31, hi = lane >> 5;
  const int lt = blockIdx.x, n = blockIdx.y;

  // ---- phase 1: x[n][c][lt*64..] -> bf16 subtiles ----
  #pragma unroll 1
  for (int ct = 0; ct < 4; ++ct) {
    const float* xg = x + ((size_t)(n * CCH + ct * 64)) * NPIX + lt * 64;
    #pragma unroll
    for (int it = 0; it < 4; ++it) {
      int row = (tid >> 4) + it * 16;
      int col = (tid & 15) * 4;
      float4 v = *reinterpret_cast<const float4*>(xg + (size_t)row * NPIX + col);
      tile[row][col] = v.x; tile[row][col + 1] = v.y;
      tile[row][col + 2] = v.z; tile[row][col + 3] = v.w;
    }
    __syncthreads();
    #pragma unroll
    for (int it = 0; it < 2; ++it) {
      int idx = tid + it * 256;
      int l = idx >> 3;
      int ch = (idx & 7) * 8;
      int c = ct * 64 + ch;
      uint4 o;
      o.x = pack2(tile[ch + 0][l], tile[ch + 1][l]);
      o.y = pack2(tile[ch + 2][l], tile[ch + 3][l]);
      o.z = pack2(tile[ch + 4][l], tile[ch + 5][l]);
      o.w = pack2(tile[ch + 6][l], tile[ch + 7][l]);
      int addr = (l >> 5) * 16384 + (c >> 4) * 1024 + ((c >> 3) & 1) * 512 + (l & 31) * 16;
      *reinterpret_cast<uint4*>(xsub + addr) = o;
    }
    __syncthreads();
  }

  // ---- phase 2: wave = o-quarter [wid*64, wid*64+64) ----
  const int o0a = wid * 64, o0b = wid * 64 + 32;
  const size_t pixrow = (size_t)n * NPIX + lt * 64;

  #pragma unroll 1
  for (int mat = 0; mat < 3; ++mat) {
    const unsigned short* W = Wbf + mat * 65536;
    const float* bias = (mat == 0) ? bb : (mat == 1) ? bc : bd;
    f32x16 a00, a01, a10, a11;  // [oi][pix-half]
    #pragma unroll
    for (int e = 0; e < 16; ++e) { a00[e] = 0.f; a01[e] = 0.f; a10[e] = 0.f; a11[e] = 0.f; }
    #pragma unroll
    for (int c0 = 0; c0 < 16; ++c0) {
      bf16x8 x0 = *reinterpret_cast<const bf16x8*>(xsub + c0 * 1024 + lane * 16);
      bf16x8 x1 = *reinterpret_cast<const bf16x8*>(xsub + 16384 + c0 * 1024 + lane * 16);
      bf16x8 w0 = *reinterpret_cast<const bf16x8*>(W + (o0a + l31) * CCH + c0 * 16 + hi * 8);
      bf16x8 w1 = *reinterpret_cast<const bf16x8*>(W + (o0b + l31) * CCH + c0 * 16 + hi * 8);
      if (mat < 2) {
        a00 = __builtin_amdgcn_mfma_f32_32x32x16_bf16(w0, x0, a00, 0, 0, 0);
        a01 = __builtin_amdgcn_mfma_f32_32x32x16_bf16(w0, x1, a01, 0, 0, 0);
        a10 = __builtin_amdgcn_mfma_f32_32x32x16_bf16(w1, x0, a10, 0, 0, 0);
        a11 = __builtin_amdgcn_mfma_f32_32x32x16_bf16(w1, x1, a11, 0, 0, 0);
      } else {
        a00 = __builtin_amdgcn_mfma_f32_32x32x16_bf16(x0, w0, a00, 0, 0, 0);
        a01 = __builtin_amdgcn_mfma_f32_32x32x16_bf16(x1, w0, a01, 0, 0, 0);
        a10 = __builtin_amdgcn_mfma_f32_32x32x16_bf16(x0, w1, a10, 0, 0, 0);
        a11 = __builtin_amdgcn_mfma_f32_32x32x16_bf16(x1, w1, a11, 0, 0, 0);
      }
    }
    if (mat < 2) {
      unsigned short* dst = (mat == 0) ? Q : K;
      #pragma unroll 1
      for (int ph = 0; ph < 2; ++ph) {
        __syncthreads();
        const f32x16& A0 = ph ? a01 : a00;
        const f32x16& A1 = ph ? a11 : a10;
        const int swz = (l31 & 15) << 4;
        #pragma unroll
        for (int r2 = 0; r2 < 8; ++r2) {
          const int r = r2 * 2;
          const int od = (r & 3) + 8 * (r >> 2) + 4 * hi;
          const int oa = o0a + od, ob = o0b + od;
          *reinterpret_cast<unsigned int*>(bounce + ((l31 * 512 + oa * 2) ^ swz)) =
              pack2(A0[r] + bias[oa], A0[r + 1] + bias[oa + 1]);
          *reinterpret_cast<unsigned int*>(bounce + ((l31 * 512 + ob * 2) ^ swz)) =
              pack2(A1[r] + bias[ob], A1[r + 1] + bias[ob + 1]);
        }
        __syncthreads();
        const int dp = tid >> 3, obase = (tid & 7) * 32;
        const int dswz = (dp & 15) << 4;
        char* gout = (char*)(dst + (pixrow + ph * 32 + dp) * CCH + obase);
        #pragma unroll
        for (int k = 0; k < 4; ++k) {
          u32x4 v = *reinterpret_cast<const u32x4*>(
              bounce + ((dp * 512 + obase * 2 + k * 16) ^ dswz));
          *reinterpret_cast<u32x4*>(gout + k * 16) = v;
        }
      }
    } else {
      // ---- V epilogue: single round, both o-halves concurrently ----
      __syncthreads();   // all waves finished xsub MFMA reads; xsub reusable
      {
        char* dstb = (wid >> 1) ? xsub : bounce;
        const int ola = (wid & 1) * 64 + l31;   // o0a + l31 - (wid>>1)*128
        const int olb = ola + 32;
        const float bva = bias[o0a + l31], bvb = bias[o0b + l31];
        const int sza = (ola & 7) << 4, szb = (olb & 7) << 4;
        #pragma unroll
        for (int r2 = 0; r2 < 8; ++r2) {
          const int r = r2 * 2;
          const int pd = (r & 3) + 8 * (r >> 2) + 4 * hi;
          *reinterpret_cast<unsigned int*>(dstb + ((ola * 128 + pd * 2) ^ sza)) =
              pack2(a00[r] + bva, a00[r + 1] + bva);
          *reinterpret_cast<unsigned int*>(dstb + ((ola * 128 + (pd + 32) * 2) ^ sza)) =
              pack2(a01[r] + bva, a01[r + 1] + bva);
          *reinterpret_cast<unsigned int*>(dstb + ((olb * 128 + pd * 2) ^ szb)) =
              pack2(a10[r] + bvb, a10[r + 1] + bvb);
          *reinterpret_cast<unsigned int*>(dstb + ((olb * 128 + (pd + 32) * 2) ^ szb)) =
              pack2(a11[r] + bvb, a11[r + 1] + bvb);
        }
      }
      __syncthreads();
      const int ol = tid >> 1, pb0 = (tid & 1) * 32;
      const int vswz = (ol & 7) << 4;
      #pragma unroll
      for (int os = 0; os < 2; ++os) {
        const char* srcb = os ? xsub : bounce;
        char* gout = (char*)(Vt + ((size_t)(n * CCH + os * 128 + ol)) * NPIX + lt * 64 + pb0);
        #pragma unroll
        for (int k = 0; k < 4; ++k) {
          u32x4 v = *reinterpret_cast<const u32x4*>(
              srcb + ((ol * 128 + pb0 * 2 + k * 16) ^ vswz));
          *reinterpret_cast<u32x4*>(gout + k * 16) = v;
        }
      }
    }
  }
}

// ---------------- attention partial: one j-half per block (plateau-frozen) ----
// 4 waves x 32 q; KVBLK=32, 64 iters, dbuf 2x32KB -> 2 blocks/CU.
// 881 TF ~= the documented plain-HIP 8-warp attention plateau (~900 TF).
// Falsified levers (R1-R6): counted-vmcnt pipeline (null), att[2] softmax/PV
// overlap (null), PV ks-major dep relief (null), LDS-free L2-direct reads
// (-127us: LDS staging IS the fast path), split-S QK chain (null).
// Occupancy pinned by unified RF: qf 64 + oacc 128 AGPR + working ~= 252/256.
__global__ __launch_bounds__(256, 2) void attn_part_kernel(
    const unsigned short* __restrict__ Q, const unsigned short* __restrict__ K,
    const unsigned short* __restrict__ Vt, unsigned short* __restrict__ Opart,
    float* __restrict__ lsumbuf) {
  __shared__ __align__(16) char smem[65536];

  const int tid = threadIdx.x;
  const int wid = tid >> 6;
  const int lane = tid & 63;
  const int l31 = lane & 31;
  const int hi = lane >> 5;
  const int lofs = lane << 4;
  const int blk = blockIdx.x;
  const int n = blk & 7;
  const int t2 = blk >> 3;
  const int half = t2 & 1;
  const int qb = t2 >> 1;
  const int q0 = qb * 128 + wid * 32;

  const unsigned short* Qg = Q + (size_t)n * NPIX * CCH;
  const char* Kg = (const char*)(K + ((size_t)n * NPIX + half * 2048) * CCH);
  const char* Vg = (const char*)(Vt + (size_t)n * CCH * NPIX + half * 2048);

  bf16x8 qf[16];
  #pragma unroll
  for (int c0 = 0; c0 < 16; ++c0)
    qf[c0] = *reinterpret_cast<const bf16x8*>(
        Qg + (size_t)(q0 + l31) * CCH + c0 * 16 + hi * 8);

  f32x16 oacc[8];
  #pragma unroll
  for (int i = 0; i < 8; ++i)
    #pragma unroll
    for (int e = 0; e < 16; ++e) oacc[i][e] = 0.f;
  float lsum = 0.f;

  const bool isK = wid < 2;
  const char* splane = isK ? Kg : Vg;
  const int sinc = isK ? 32 * 512 : 64;
  int soff[8];
  #pragma unroll
  for (int g = 0; g < 8; ++g) {
    int s = ((wid & 1) << 3) + g;
    if (isK) {
      soff[g] = l31 * 512 + s * 32 + hi * 16;
    } else {
      int cb = s >> 1, kk2 = s & 1;
      soff[g] = (cb * 32 + l31) * 8192 + (kk2 * 16 + hi * 8) * 2;
    }
  }

  auto STAGE = [&](int par, int adv) {
    #pragma unroll
    for (int g = 0; g < 8; ++g)
      gld_lds16(splane + (size_t)soff[g] + (size_t)adv,
                smem + par * 32768 + (((wid << 3) + g) << 10));
  };

  STAGE(0, 0);
  __syncthreads();

  #pragma unroll 1
  for (int t = 0; t < 64; ++t) {
    const int par = t & 1;
    const char* kb = smem + par * 32768;
    const char* vb = kb + 16384;

    f32x16 S;
    #pragma unroll
    for (int e = 0; e < 16; ++e) S[e] = 0.f;
    __builtin_amdgcn_s_setprio(1);
    #pragma unroll
    for (int c0 = 0; c0 < 16; ++c0) {
      bf16x8 kf = *reinterpret_cast<const bf16x8*>(kb + c0 * 1024 + lofs);
      S = __builtin_amdgcn_mfma_f32_32x32x16_bf16(kf, qf[c0], S, 0, 0, 0);
    }
    __builtin_amdgcn_s_setprio(0);

    // prefetch of next tile issued while softmax runs
    if (t < 63) STAGE(par ^ 1, (t + 1) * sinc);

    // ---- fixed-offset softmax: P = exp2(S*log2e - 101), pack via cvt_pk ----
    float rsum = 0.f;
    unsigned int pw[8];
    #pragma unroll
    for (int i = 0; i < 8; ++i) {
      float p0 = exp2f(fmaf(S[2 * i],     1.44269504f, -101.0f));
      float p1 = exp2f(fmaf(S[2 * i + 1], 1.44269504f, -101.0f));
      rsum += p0 + p1;
      unsigned int r;
      asm("v_cvt_pk_bf16_f32 %0, %1, %2" : "=v"(r) : "v"(p0), "v"(p1));
      pw[i] = r;
    }
    lsum += rsum;

    // ---- P re-layout via permlane32_swap ----
    unsigned int s0a = pw[0], s0b = pw[2];
    unsigned int s1a = pw[1], s1b = pw[3];
    unsigned int s2a = pw[4], s2b = pw[6];
    unsigned int s3a = pw[5], s3b = pw[7];
    asm volatile("v_permlane32_swap_b32 %0, %1" : "+v"(s0a), "+v"(s0b));
    asm volatile("v_permlane32_swap_b32 %0, %1" : "+v"(s1a), "+v"(s1b));
    asm volatile("v_permlane32_swap_b32 %0, %1" : "+v"(s2a), "+v"(s2b));
    asm volatile("v_permlane32_swap_b32 %0, %1" : "+v"(s3a), "+v"(s3b));
    u32x4 f0, f1;
    f0[0] = s0a; f0[1] = s1a; f0[2] = s0b; f0[3] = s1b;
    f1[0] = s2a; f1[1] = s3a; f1[2] = s2b; f1[3] = s3b;
    bf16x8 pa0 = __builtin_bit_cast(bf16x8, f0);
    bf16x8 pa1 = __builtin_bit_cast(bf16x8, f1);

    __builtin_amdgcn_s_setprio(1);
    #pragma unroll
    for (int cb = 0; cb < 8; ++cb) {
      bf16x8 v0 = *reinterpret_cast<const bf16x8*>(vb + (cb * 2 + 0) * 1024 + lofs);
      oacc[cb] = __builtin_amdgcn_mfma_f32_32x32x16_bf16(pa0, v0, oacc[cb], 0, 0, 0);
    }
    #pragma unroll
    for (int cb = 0; cb < 8; ++cb) {
      bf16x8 v1 = *reinterpret_cast<const bf16x8*>(vb + (cb * 2 + 1) * 1024 + lofs);
      oacc[cb] = __builtin_amdgcn_mfma_f32_32x32x16_bf16(pa1, v1, oacc[cb], 0, 0, 0);
    }
    __builtin_amdgcn_s_setprio(0);

    __syncthreads();
  }

  lsum += __shfl_xor(lsum, 32);
  char* slab = (char*)Opart + (size_t)blk * 65536;
  #pragma unroll
  for (int cb = 0; cb < 8; ++cb) {
    u32x4 u0, u1;
    u0[0] = pack2(oacc[cb][0],  oacc[cb][1]);
    u0[1] = pack2(oacc[cb][2],  oacc[cb][3]);
    u0[2] = pack2(oacc[cb][4],  oacc[cb][5]);
    u0[3] = pack2(oacc[cb][6],  oacc[cb][7]);
    u1[0] = pack2(oacc[cb][8],  oacc[cb][9]);
    u1[1] = pack2(oacc[cb][10], oacc[cb][11]);
    u1[2] = pack2(oacc[cb][12], oacc[cb][13]);
    u1[3] = pack2(oacc[cb][14], oacc[cb][15]);
    *reinterpret_cast<u32x4*>(slab + (cb * 2 + 0) * 4096 + tid * 16) = u0;
    *reinterpret_cast<u32x4*>(slab + (cb * 2 + 1) * 4096 + tid * 16) = u1;
  }
  if (hi == 0) lsumbuf[blk * 128 + wid * 32 + l31] = lsum;
}

// ---------------- merge halves + normalize + residual + transpose ----------------
// grid 256 = (n, qb); 512 threads (8 waves -> better latency hiding).
__global__ __launch_bounds__(512) void merge_kernel(
    const unsigned short* __restrict__ Opart, const float* __restrict__ lsumbuf,
    const float* __restrict__ x, const float* __restrict__ alpha_p,
    float* __restrict__ out) {
  __shared__ float T[32768];   // [c 0..255][q' 0..127], elem = c*128 + (q'^(c&28))
  __shared__ float Lq[128];

  const int tid = threadIdx.x;
  const int pr8 = tid >> 6;
  const int lane = tid & 63;
  const int l31 = lane & 31;
  const int hi = lane >> 5;
  const int qsub = pr8 & 3;
  const int cbh = pr8 >> 2;
  const int atid = qsub * 64 + lane;    // matching attn-slab thread index
  const int m = blockIdx.x;
  const int n = m & 7;
  const int qb = m >> 3;
  const int blkA = n + 8 * (0 + 2 * qb);
  const int blkB = n + 8 * (1 + 2 * qb);

  if (tid < 128)
    Lq[tid] = alpha_p[0] / (lsumbuf[blkA * 128 + tid] + lsumbuf[blkB * 128 + tid]);
  __syncthreads();

  const char* sa = (const char*)Opart + (size_t)blkA * 65536;
  const char* sb = (const char*)Opart + (size_t)blkB * 65536;

  #pragma unroll
  for (int cbi = 0; cbi < 4; ++cbi) {
    const int cb = cbh * 4 + cbi;
    const int c = cb * 32 + l31;
    const int swz = c & 28;
    #pragma unroll
    for (int h = 0; h < 2; ++h) {
      u32x4 a = *reinterpret_cast<const u32x4*>(sa + (cb * 2 + h) * 4096 + atid * 16);
      u32x4 b = *reinterpret_cast<const u32x4*>(sb + (cb * 2 + h) * 4096 + atid * 16);
      #pragma unroll
      for (int w = 0; w < 4; ++w) {
        const int r = h * 8 + w * 2;
        float v0 = bfu((unsigned short)(a[w] & 0xFFFF)) + bfu((unsigned short)(b[w] & 0xFFFF));
        float v1 = bfu((unsigned short)(a[w] >> 16)) + bfu((unsigned short)(b[w] >> 16));
        const int q0l = qsub * 32 + ((r) & 3) + 8 * ((r) >> 2) + 4 * hi;
        const int q1l = q0l + 1;
        T[c * 128 + (q0l ^ swz)] = v0 * Lq[q0l];
        T[c * 128 + (q1l ^ swz)] = v1 * Lq[q1l];
      }
    }
  }
  __syncthreads();

  // write out: 16 sweeps, 16 c-rows per sweep, float4 per thread
  const int l0 = (tid & 31) * 4;
  #pragma unroll 4
  for (int sw = 0; sw < 16; ++sw) {
    const int c = (tid >> 5) + sw * 16;
    const float* src = &T[c * 128 + (l0 ^ (c & 28))];
    float4 v = *reinterpret_cast<const float4*>(src);
    const size_t g = ((size_t)n * CCH + c) * NPIX + qb * 128 + l0;
    float4 xi = *reinterpret_cast<const float4*>(x + g);
    float4 o;
    o.x = v.x + xi.x; o.y = v.y + xi.y; o.z = v.z + xi.z; o.w = v.w + xi.w;
    *reinterpret_cast<float4*>(out + g) = o;
  }
}

extern "C" void kernel_launch(void* const* d_in, const int* in_sizes, int n_in,
                              void* d_out, int out_size, void* d_ws, size_t ws_size,
                              hipStream_t stream) {
  const float* x  = (const float*)d_in[0];
  const float* Wb = (const float*)d_in[1];
  const float* bb = (const float*)d_in[2];
  const float* Wc = (const float*)d_in[3];
  const float* bc = (const float*)d_in[4];
  const float* Wd = (const float*)d_in[5];
  const float* bd = (const float*)d_in[6];
  const float* alpha = (const float*)d_in[7];
  float* out = (float*)d_out;
  char* ws = (char*)d_ws;

  unsigned short* Wbf   = (unsigned short*)(ws);                //    393,216 B
  unsigned short* Q     = (unsigned short*)(ws + 393216);       // 16,777,216 B
  unsigned short* K     = (unsigned short*)(ws + 17170432);     // 16,777,216 B
  unsigned short* Vt    = (unsigned short*)(ws + 33947648);     // 16,777,216 B
  unsigned short* Opart = (unsigned short*)(ws + 50724864);     // 33,554,432 B
  float*          lsumb = (float*)(ws + 84279296);              //    262,144 B

  convert_w_kernel<<<dim3(64, 3), 256, 0, stream>>>(Wb, Wc, Wd, Wbf);
  fused_proj_kernel<<<dim3(64, 8), 256, 0, stream>>>(x, Wbf, bb, bc, bd, Q, K, Vt);
  attn_part_kernel<<<dim3(512), 256, 0, stream>>>(Q, K, Vt, Opart, lsumb);
  merge_kernel<<<dim3(256), 512, 0, stream>>>(Opart, lsumb, x, alpha, out);
}